// Round 4
// baseline (206.954 us; speedup 1.0000x reference)
//
#include <hip/hip_runtime.h>
#include <stdint.h>

// ---------------------------------------------------------------------------
// DS_MultiHeadLatentAttention, round 12 (= round 11 resubmit; container flake).
// attn9 = attn8 with the paired q-tiles (tA=pair, tB=31-pair) FUSED into one
// K/V sweep: chunks 0..tB staged once, applied to tile B always and tile A
// while c<=tA. Cuts staged chunks 18.5->12.75 avg and barriers ~55->~38 per
// block at identical compute (33 chunk-units/block, still balanced).
// Q fragments hoisted (4 ld8). Ps reused B-then-A per wave (no extra LDS).
// s_setprio(1) wraps QK and PV MFMA clusters (T5; phase-split now exists).
// Same counted-vmcnt pipeline: issue V(c)+K(c+2) -> vmcnt(4) [K(c)] -> B1 ->
// QK_B+sm_B (covers V) -> vmcnt(2) [V] -> B2 -> PV_B, QK_A+sm_A, PV_A -> B3.
// LDS 67KB -> 2 blocks/CU. prep/gemms unchanged.
// Dispatches: prep, gemmQLat(640), gemmKV(1024), attn(512), gemmO(512).
// Workspace (34 MB, time-phased):
//   [0,8M)   Qp      [8,16M)  Kb -> Kp      [16,24M) Qb -> VpT
//   [24,32M) WqT(2M)|Lat(2M)|WdT(.5M)|WkvT(1M) -> Attn
//   [32,34M) WoT
// ---------------------------------------------------------------------------

#define DM 1024
#define NH 16
#define DK 64
#define LL 2048

typedef float  f32x4  __attribute__((ext_vector_type(4)));
typedef __bf16 bf16x8 __attribute__((ext_vector_type(8)));
typedef short  s16x8  __attribute__((ext_vector_type(8)));

__device__ __forceinline__ unsigned short f2bf(float f) {
    union { float f; unsigned int u; } v; v.f = f;
    return (unsigned short)((v.u + 0x7fffu + ((v.u >> 16) & 1u)) >> 16);
}
__device__ __forceinline__ unsigned int pack2(float a, float b) {
    return (unsigned int)f2bf(a) | ((unsigned int)f2bf(b) << 16);
}
// truncating pack (exp values only)
__device__ __forceinline__ unsigned int packt(float a, float b) {
    union { float f; unsigned int u; } x, y; x.f = a; y.f = b;
    return (x.u >> 16) | (y.u & 0xffff0000u);
}
__device__ __forceinline__ bf16x8 ld8(const unsigned short* p) {
    s16x8 s = *(const s16x8*)p;
    return __builtin_bit_cast(bf16x8, s);
}
__device__ __forceinline__ void gl16(const void* g, void* l) {
    __builtin_amdgcn_global_load_lds((__attribute__((address_space(1))) void*)(g),
                                     (__attribute__((address_space(3))) void*)(l),
                                     16, 0, 0);
}

// ---------------------------------------------------------------------------
// prep: 5 weight transposes (fp32 [K][N] -> bf16 [N][K]) + queries/keys
// fp32 -> bf16. Grid = 4864.
// ---------------------------------------------------------------------------
__global__ __launch_bounds__(256)
void prep_k(const float* __restrict__ Wq, const float* __restrict__ Wd,
            const float* __restrict__ Wk, const float* __restrict__ Wv,
            const float* __restrict__ Wo, const float* __restrict__ queries,
            const float* __restrict__ keys,
            unsigned short* __restrict__ WqT, unsigned short* __restrict__ WdT,
            unsigned short* __restrict__ WkvT, unsigned short* __restrict__ WoT,
            unsigned short* __restrict__ Qb, unsigned short* __restrict__ Kb) {
    int bid = blockIdx.x;
    const int t = threadIdx.x;

    const float* W; unsigned short* WT; int TK, TN;
    if (bid < 1024)      { W = Wq; WT = WqT;  TK = 1024; TN = 1024; }
    else if (bid < 1280) { bid -= 1024; W = Wd; WT = WdT; TK = 1024; TN = 256; }
    else if (bid < 1536) { bid -= 1280; W = Wk; WT = WkvT; TK = 256; TN = 1024; }
    else if (bid < 1792) { bid -= 1536; W = Wv; WT = WkvT + (size_t)1024 * 256; TK = 256; TN = 1024; }
    else if (bid < 2816) { bid -= 1792; W = Wo; WT = WoT;  TK = 1024; TN = 1024; }
    else {
        bid -= 2816;
        const float* src; unsigned short* dst;
        if (bid < 1024) { src = queries; dst = Qb; }
        else            { bid -= 1024; src = keys; dst = Kb; }
        const size_t base = (size_t)bid * 4096;
#pragma unroll
        for (int i = 0; i < 4; ++i) {
            float4 f = *(const float4*)(src + base + (size_t)(i * 256 + t) * 4);
            uint2 u = { pack2(f.x, f.y), pack2(f.z, f.w) };
            *(uint2*)(dst + base + (size_t)(i * 256 + t) * 4) = u;
        }
        return;
    }
    __shared__ float tile[32][33];
    const int tx = t & 31, ty = t >> 5;
    const int bx = bid % (TK / 32), by = bid / (TK / 32);
    const int k0 = bx * 32, n0 = by * 32;
#pragma unroll
    for (int i = 0; i < 4; ++i)
        tile[ty + 8 * i][tx] = W[(size_t)(k0 + ty + 8 * i) * TN + n0 + tx];
    __syncthreads();
#pragma unroll
    for (int i = 0; i < 4; ++i)
        WT[(size_t)(n0 + ty + 8 * i) * TK + k0 + tx] = f2bf(tile[tx][ty + 8 * i]);
}

// ---------------------------------------------------------------------------
// GEMM staging + compute helpers (128x64 tile, BK=64).
// ---------------------------------------------------------------------------
__device__ __forceinline__ void stage6(const unsigned short* gA, const unsigned short* gB,
                                       int kk, int K,
                                       unsigned short* lA, unsigned short* lB) {
#pragma unroll
    for (int s = 0; s < 4; ++s) gl16(gA + kk + (size_t)s * 8 * K, lA + s * 512);
#pragma unroll
    for (int s = 0; s < 2; ++s) gl16(gB + kk + (size_t)s * 8 * K, lB + s * 512);
}

__device__ __forceinline__ void mfma16(const unsigned short* As, const unsigned short* Bs,
                                       const int aoff[4][2], const int boff[2][2],
                                       f32x4 acc[4][2]) {
#pragma unroll
    for (int ks = 0; ks < 2; ++ks) {
        bf16x8 a[4], b[2];
#pragma unroll
        for (int i = 0; i < 4; ++i) a[i] = ld8(As + aoff[i][ks]);
#pragma unroll
        for (int j = 0; j < 2; ++j) b[j] = ld8(Bs + boff[j][ks]);
#pragma unroll
        for (int i = 0; i < 4; ++i)
#pragma unroll
            for (int j = 0; j < 2; ++j)
                acc[i][j] = __builtin_amdgcn_mfma_f32_16x16x32_bf16(a[i], b[j], acc[i][j], 0, 0, 0);
    }
}

// ---------------------------------------------------------------------------
// GEMM 128(M) x 64(N) tile, BK=64, 4 waves 2x2 (wave = 64m x 32n, 4x2 accs).
// LDS double-buffer (Sh0/Sh1, compile-time selection), one barrier per iter.
// XCD-clustered: xcd = bid&7 sweeps all n over a small m-window.
// MODE 0: fused Q+Lat (K=1024). bid<512: Qb@WqT+bq -> Qp bf16 [row*1024].
//         bid>=512 (128 blocks): Kb@WdT+bd -> Lat bf16 [row*256].
// MODE 1: Attn@WoT+bo -> f32 [row*1024]. grid 512, K=1024.
// MODE 2: fused K|V (K=256, N=2048): col<1024 -> Kp bf16 [row*1024];
//         col>=1024 -> VpT [b][col-1024][l] via LDS-transposed epilogue.
// ---------------------------------------------------------------------------
template<int MODE>
__global__ __launch_bounds__(256)
void gemm_k(const unsigned short* __restrict__ Ap, const unsigned short* __restrict__ Bt,
            const float* __restrict__ bias, void* __restrict__ Cp,
            const unsigned short* __restrict__ Ap2, const unsigned short* __restrict__ Bt2,
            const float* __restrict__ bias2, void* __restrict__ Cp2,
            int K) {
    __shared__ unsigned short Sh0[12288];     // As0 8192 + Bs0 4096 shorts (24 KB)
    __shared__ unsigned short Sh1[12288];     // As1 + Bs1 (24 KB)

    int bid = blockIdx.x;
    const unsigned short* A;
    const unsigned short* B;
    const float* bs;
    bool second = false;
    int m0, n0;
    if (MODE == 0 && bid >= 512) {            // Lat part: 128 blocks, N=256
        bid -= 512; A = Ap2; B = Bt2; bs = bias2; second = true;
        const int xcd = bid & 7, s = bid >> 3;            // s in [0,16)
        n0 = (s & 3) * 64; m0 = (xcd * 4 + (s >> 2)) * 128;
    } else {
        A = Ap; B = Bt; bs = bias;
        const int xcd = bid & 7, s = bid >> 3;
        if (MODE == 2) { n0 = (s & 31) * 64; m0 = (xcd * 4 + (s >> 5)) * 128; }
        else           { n0 = (s & 15) * 64; m0 = (xcd * 4 + (s >> 4)) * 128; }
    }

    const int t = threadIdx.x, lane = t & 63, wv = t >> 6;
    const int quad = lane >> 4, l15 = lane & 15;

    const int lr8 = lane >> 3;                 // 0..7
    const int g8 = (lane & 7) ^ (lr8 & 7);     // swizzled k-chunk
    const unsigned short* gA = A + (size_t)(m0 + wv * 32 + lr8) * K + g8 * 8;
    const unsigned short* gB = B + (size_t)(n0 + wv * 16 + lr8) * K + g8 * 8;
    unsigned short* lA0 = Sh0 + wv * 2048;
    unsigned short* lB0 = Sh0 + 8192 + wv * 1024;
    unsigned short* lA1 = Sh1 + wv * 2048;
    unsigned short* lB1 = Sh1 + 8192 + wv * 1024;

    int aoff[4][2], boff[2][2];
#pragma unroll
    for (int i = 0; i < 4; ++i) {
        const int ra = (wv >> 1) * 64 + i * 16 + l15;
#pragma unroll
        for (int ks = 0; ks < 2; ++ks)
            aoff[i][ks] = ra * 64 + (((ks * 4 + quad) ^ (ra & 7)) << 3);
    }
#pragma unroll
    for (int j = 0; j < 2; ++j) {
        const int rb = (wv & 1) * 32 + j * 16 + l15;
#pragma unroll
        for (int ks = 0; ks < 2; ++ks)
            boff[j][ks] = rb * 64 + (((ks * 4 + quad) ^ (rb & 7)) << 3);
    }

    f32x4 acc[4][2] = {};
    const int niter = K >> 6;                  // 16 or 4 (always even)

    stage6(gA, gB, 0, K, lA0, lB0);
    __syncthreads();                           // tile 0 resident in Sh0
    for (int it = 0; it < niter; it += 2) {
        const int kk = it << 6;
        // even iter: prefetch -> Sh1, compute Sh0
        if (it + 1 < niter) stage6(gA, gB, kk + 64, K, lA1, lB1);
        mfma16(Sh0, Sh0 + 8192, aoff, boff, acc);
        __syncthreads();                       // drains Sh1 gl16s (overlapped)
        if (it + 1 < niter) {
            // odd iter: prefetch -> Sh0, compute Sh1
            if (it + 2 < niter) stage6(gA, gB, kk + 128, K, lA0, lB0);
            mfma16(Sh1, Sh1 + 8192, aoff, boff, acc);
            __syncthreads();
        }
    }

    const bool isV = (MODE == 2) && (n0 >= 1024);
    if (!isV) {
#pragma unroll
        for (int j = 0; j < 2; ++j) {
            const int col = n0 + (wv & 1) * 32 + j * 16 + l15;
            const float bvv = bs[col];
#pragma unroll
            for (int i = 0; i < 4; ++i) {
                const int rowb = m0 + (wv >> 1) * 64 + i * 16 + quad * 4;
#pragma unroll
                for (int r = 0; r < 4; ++r) {
                    const float v = acc[i][j][r] + bvv;
                    const int row = rowb + r;
                    if (MODE == 1)
                        ((float*)Cp)[(size_t)row * 1024 + col] = v;
                    else if (second)
                        ((unsigned short*)Cp2)[(size_t)row * 256 + col] = f2bf(v);
                    else
                        ((unsigned short*)Cp)[(size_t)row * 1024 + col] = f2bf(v);
                }
            }
        }
    } else {
        // V part: transpose 128tok x 64d tile through LDS, store coalesced
        // to VpT[(b*1024 + d)*2048 + l].  Ld layout: [d][tok], stride 136.
        unsigned short* Ld = Sh0;               // 64*136 shorts = 17408 B
#pragma unroll
        for (int j = 0; j < 2; ++j) {
            const int dloc = (wv & 1) * 32 + j * 16 + l15;
            const float bvv = bias2[(n0 - 1024) + dloc];
#pragma unroll
            for (int i = 0; i < 4; ++i) {
                const int tokb = (wv >> 1) * 64 + i * 16 + quad * 4;
#pragma unroll
                for (int r = 0; r < 4; ++r)
                    Ld[dloc * 136 + tokb + r] = f2bf(acc[i][j][r] + bvv);
            }
        }
        __syncthreads();
        const int dloc = t >> 2;                // 0..63
        const int tk0 = (t & 3) * 32;           // 0,32,64,96
        const int bb = m0 >> 11;
        unsigned short* dst = (unsigned short*)Cp2 +
            ((size_t)bb * 1024 + (n0 - 1024) + dloc) * LL + (m0 & (LL - 1)) + tk0;
        const unsigned short* srcp = Ld + dloc * 136 + tk0;
#pragma unroll
        for (int c = 0; c < 4; ++c)
            *(uint4*)(dst + c * 8) = *(const uint4*)(srcp + c * 8);
    }
}

// ---------------------------------------------------------------------------
// attn9 helpers: swapped QK^T + fixed-shift softmax -> Ps; PV accumulate.
// ---------------------------------------------------------------------------
__device__ __forceinline__ void qk_sm(const unsigned short* Kc,
        const bf16x8 aq0, const bf16x8 aq1, int rowq, int kt, bool diag,
        int l15, int quad, int sw, unsigned short* PsW, float& lsum) {
#pragma unroll
    for (int sub = 0; sub < 4; ++sub) {
        const int base2 = (sub * 16 + l15) * 64;
        const bf16x8 k0 = ld8(Kc + base2 + ((quad ^ sw) << 3));
        const bf16x8 k1 = ld8(Kc + base2 + (((4 + quad) ^ sw) << 3));
        f32x4 ss = {};
        __builtin_amdgcn_s_setprio(1);
        ss = __builtin_amdgcn_mfma_f32_16x16x32_bf16(k0, aq0, ss, 0, 0, 0);
        ss = __builtin_amdgcn_mfma_f32_16x16x32_bf16(k1, aq1, ss, 0, 0, 0);
        __builtin_amdgcn_s_setprio(0);
        float e[4];
        if (diag) {                            // diagonal chunk: causal mask
            const int kb4 = kt + sub * 16 + quad * 4;
#pragma unroll
            for (int r = 0; r < 4; ++r) {
                const float x = exp2f(fmaf(ss[r], 0.18033688011112042f, -16.0f));
                e[r] = (kb4 + r > rowq) ? 0.f : x;
            }
        } else {                               // interior: no mask
#pragma unroll
            for (int r = 0; r < 4; ++r)
                e[r] = exp2f(fmaf(ss[r], 0.18033688011112042f, -16.0f));
        }
        lsum += (e[0] + e[1]) + (e[2] + e[3]);
        uint2 w2;
        w2.x = packt(e[0], e[1]);
        w2.y = packt(e[2], e[3]);
        *(uint2*)(PsW + l15 * 72 + sub * 16 + quad * 4) = w2;
    }
}

__device__ __forceinline__ void pv_acc(const unsigned short* PsW, const unsigned short* Vg,
        int l15, int quad, int sw, f32x4 acc[4]) {
#pragma unroll
    for (int ks = 0; ks < 2; ++ks) {
        const bf16x8 ap = ld8(PsW + l15 * 72 + ks * 32 + quad * 8);
        __builtin_amdgcn_s_setprio(1);
#pragma unroll
        for (int sub = 0; sub < 4; ++sub) {
            const bf16x8 bv = ld8(Vg + (sub * 16 + l15) * 64 + (((ks * 4 + quad) ^ sw) << 3));
            acc[sub] = __builtin_amdgcn_mfma_f32_16x16x32_bf16(ap, bv, acc[sub], 0, 0, 0);
        }
        __builtin_amdgcn_s_setprio(0);
    }
}

// ---------------------------------------------------------------------------
// attn9: grid 512 = 32 combos x 16 pairs. Block fuses tiles tA=pair and
// tB=31-pair over ONE chunk sweep c=0..tB (parity-split over 2 groups of 4
// waves; each wave owns 16 q-rows of each tile). Counted-vmcnt pipeline:
// K double-buffered, V single (guarded by B3). Per iter:
//   issue V(c), K(c+2) | vmcnt(4) B1 | QK_B+sm_B | vmcnt(2) B2 |
//   PV_B | (QK_A+sm_A, PV_A if c<=tA) | B3
// Epilogue: combine grp1->grp0 via CB (overlays Ks), tile A then tile B.
// LDS: Ks 32K + Vs 16K + Ps 18K = 67K -> 2 blocks/CU (16 waves).
// ---------------------------------------------------------------------------
__global__ __launch_bounds__(512, 4)
void attn9_k(const unsigned short* __restrict__ Qp,
             const unsigned short* __restrict__ Kp,
             const unsigned short* __restrict__ VpT,
             unsigned short* __restrict__ Op) {
    __shared__ unsigned short Ks[2][2][4096];  // [grp][buf][64k x 64d]
    __shared__ unsigned short Vs[2][4096];     // [grp][64d x 64k]
    __shared__ unsigned short Ps[8][1152];     // per-wave [16q][72k]
    float* CB = (float*)&Ks[0][0][0];          // epilogue combine (20KB < 32KB)

    const int t = threadIdx.x, lane = t & 63, wv = t >> 6;
    const int grp = wv >> 2, w4 = wv & 3;
    const int quad = lane >> 4, l15 = lane & 15;

    const int bid = blockIdx.x;
    const int xcd = bid & 7, s = bid >> 3;
    const int pair = s & 15;
    const int combo = xcd * 4 + (s >> 4);      // 4 combos per XCD (L2 locality)
    const int h = combo & 15, b = combo >> 4;

    const int tA = pair, tB = 31 - pair;       // tA < 16 <= tB

    const int srow = w4 * 16 + (lane >> 3);
    const int g8 = (lane & 7) ^ ((lane >> 3) & 7);
    const int sw = l15 & 7;
    unsigned short* PsW = Ps[wv];

    const unsigned short* Kbase = Kp + (size_t)(b * LL + srow) * DM + h * DK + g8 * 8;
    const unsigned short* Vbase = VpT + ((size_t)(b * NH + h) * DK + srow) * LL + g8 * 8;
    unsigned short* lV = &Vs[grp][w4 * 1024];

    const int rowqA = tA * 64 + w4 * 16 + l15;
    const int rowqB = tB * 64 + w4 * 16 + l15;
    const unsigned short* qpA = Qp + (size_t)(b * LL + rowqA) * DM + h * DK;
    const unsigned short* qpB = Qp + (size_t)(b * LL + rowqB) * DM + h * DK;
    const bf16x8 aqA0 = ld8(qpA + quad * 8), aqA1 = ld8(qpA + 32 + quad * 8);
    const bf16x8 aqB0 = ld8(qpB + quad * 8), aqB1 = ld8(qpB + 32 + quad * 8);

    f32x4 accA[4] = {}, accB[4] = {};
    float lsumA = 0.f, lsumB = 0.f;

    // prologue: stage K(grp) -> Ks[grp][0]
    {
        const unsigned short* kg = Kbase + (size_t)(grp * 64) * DM;
        unsigned short* lK = &Ks[grp][0][w4 * 1024];
        gl16(kg, lK); gl16(kg + (size_t)8 * DM, lK + 512);
    }
    const int lastc = tB - ((tB ^ grp) & 1);   // last parity-grp chunk <= tB

    const int nit = tB / 2 + 1;
    for (int it = 0; it < nit; ++it) {
        const int c = 2 * it + grp;            // wave-uniform
        const int cur = it & 1;
        const bool activeB = (c <= tB);        // false only on grp1 tail iter
        const bool activeA = (c <= tA);
        const int kt = c * 64;

        if (activeB) {
            // issue V(c) -> Vs[grp] (consumed after B2 this iter)
            const unsigned short* vg = Vbase + kt;
            gl16(vg, lV); gl16(vg + (size_t)8 * LL, lV + 512);
            // issue K(c+2) -> Ks[grp][cur^1] (clamped: uniform vmcnt)
            const int c2 = (c + 2 <= lastc) ? (c + 2) : lastc;
            const unsigned short* kg = Kbase + (size_t)(c2 * 64) * DM;
            unsigned short* lK = &Ks[grp][cur ^ 1][w4 * 1024];
            gl16(kg, lK); gl16(kg + (size_t)8 * DM, lK + 512);
        }
        asm volatile("s_waitcnt vmcnt(4)" ::: "memory");  // K(c) landed
        __builtin_amdgcn_s_barrier();                     // B1
        __builtin_amdgcn_sched_barrier(0);

        const unsigned short* Kc = Ks[grp][cur];
        if (activeB)
            qk_sm(Kc, aqB0, aqB1, rowqB, kt, c == tB, l15, quad, sw, PsW, lsumB);

        asm volatile("s_waitcnt vmcnt(2)" ::: "memory");  // V(c) landed
        __builtin_amdgcn_s_barrier();                     // B2
        __builtin_amdgcn_sched_barrier(0);

        if (activeB)
            pv_acc(PsW, &Vs[grp][0], l15, quad, sw, accB);
        if (activeA) {
            qk_sm(Kc, aqA0, aqA1, rowqA, kt, c == tA, l15, quad, sw, PsW, lsumA);
            pv_acc(PsW, &Vs[grp][0], l15, quad, sw, accA);
        }
        __builtin_amdgcn_s_barrier();                     // B3: Vs/Ks free
        __builtin_amdgcn_sched_barrier(0);
    }

    // combine even/odd k-parity groups, normalize, write out (tile A, then B)
    __syncthreads();                           // full drain (leftover K issue)
    const int base = (w4 * 64 + lane) * 20;
    if (grp == 1) {
#pragma unroll
        for (int sub = 0; sub < 4; ++sub)
#pragma unroll
            for (int r = 0; r < 4; ++r) CB[base + sub * 4 + r] = accA[sub][r];
        CB[base + 16] = lsumA;
    }
    __syncthreads();
    if (grp == 0) {
#pragma unroll
        for (int sub = 0; sub < 4; ++sub)
#pragma unroll
            for (int r = 0; r < 4; ++r) accA[sub][r] += CB[base + sub * 4 + r];
        lsumA += CB[base + 16];
        lsumA += __shfl_xor(lsumA, 16, 64);
        lsumA += __shfl_xor(lsumA, 32, 64);
        const float inv = __builtin_amdgcn_rcpf(lsumA);
        float invr[4];
#pragma unroll
        for (int r = 0; r < 4; ++r) invr[r] = __shfl(inv, quad * 4 + r, 64);
#pragma unroll
        for (int sub = 0; sub < 4; ++sub)
#pragma unroll
            for (int r = 0; r < 4; ++r)
                Op[(size_t)(b * LL + tA * 64 + w4 * 16 + quad * 4 + r) * DM + h * DK + sub * 16 + l15] =
                    f2bf(accA[sub][r] * invr[r]);
    }
    __syncthreads();                           // CB reads done before reuse
    if (grp == 1) {
#pragma unroll
        for (int sub = 0; sub < 4; ++sub)
#pragma unroll
            for (int r = 0; r < 4; ++r) CB[base + sub * 4 + r] = accB[sub][r];
        CB[base + 16] = lsumB;
    }
    __syncthreads();
    if (grp == 0) {
#pragma unroll
        for (int sub = 0; sub < 4; ++sub)
#pragma unroll
            for (int r = 0; r < 4; ++r) accB[sub][r] += CB[base + sub * 4 + r];
        lsumB += CB[base + 16];
        lsumB += __shfl_xor(lsumB, 16, 64);
        lsumB += __shfl_xor(lsumB, 32, 64);
        const float inv = __builtin_amdgcn_rcpf(lsumB);
        float invr[4];
#pragma unroll
        for (int r = 0; r < 4; ++r) invr[r] = __shfl(inv, quad * 4 + r, 64);
#pragma unroll
        for (int sub = 0; sub < 4; ++sub)
#pragma unroll
            for (int r = 0; r < 4; ++r)
                Op[(size_t)(b * LL + tB * 64 + w4 * 16 + quad * 4 + r) * DM + h * DK + sub * 16 + l15] =
                    f2bf(accB[sub][r] * invr[r]);
    }
}

// ---------------------------------------------------------------------------
extern "C" void kernel_launch(void* const* d_in, const int* in_sizes, int n_in,
                              void* d_out, int out_size, void* d_ws, size_t ws_size,
                              hipStream_t stream) {
    const float* queries = (const float*)d_in[0];
    const float* keys    = (const float*)d_in[1];
    const float* Wq = (const float*)d_in[3];  const float* bq = (const float*)d_in[4];
    const float* Wd = (const float*)d_in[5];  const float* bd = (const float*)d_in[6];
    const float* Wk = (const float*)d_in[7];  const float* bk = (const float*)d_in[8];
    const float* Wv = (const float*)d_in[9];  const float* bv = (const float*)d_in[10];
    const float* Wo = (const float*)d_in[11]; const float* bo = (const float*)d_in[12];

    char* ws = (char*)d_ws;
    const size_t MB = 1048576;
    unsigned short* Qp   = (unsigned short*)(ws);
    unsigned short* Kb   = (unsigned short*)(ws + 8 * MB);
    unsigned short* Kp   = (unsigned short*)(ws + 8 * MB);
    unsigned short* Qb   = (unsigned short*)(ws + 16 * MB);
    unsigned short* VpT  = (unsigned short*)(ws + 16 * MB);
    unsigned short* WqT  = (unsigned short*)(ws + 24 * MB);
    unsigned short* Lat  = (unsigned short*)(ws + 26 * MB);
    unsigned short* WdT  = (unsigned short*)(ws + 28 * MB);
    unsigned short* WkvT = (unsigned short*)(ws + 28 * MB + 524288);
    unsigned short* Attn = (unsigned short*)(ws + 24 * MB);
    unsigned short* WoT  = (unsigned short*)(ws + 32 * MB);

    prep_k<<<4864, 256, 0, stream>>>(Wq, Wd, Wk, Wv, Wo, queries, keys,
                                     WqT, WdT, WkvT, WoT, Qb, Kb);
    gemm_k<0><<<640, 256, 0, stream>>>(Qb, WqT, bq, Qp, Kb, WdT, bd, Lat, 1024);
    gemm_k<2><<<1024, 256, 0, stream>>>(Lat, WkvT, bk, Kp, nullptr, nullptr, bv, VpT, 256);
    attn9_k<<<512, 512, 0, stream>>>(Qp, Kp, VpT, Attn);
    gemm_k<1><<<512, 256, 0, stream>>>(Attn, WoT, bo, d_out, nullptr, nullptr, nullptr, nullptr, 1024);
}

// Round 5
// 202.195 us; speedup vs baseline: 1.0235x; 1.0235x over previous
//
#include <hip/hip_runtime.h>
#include <stdint.h>

// ---------------------------------------------------------------------------
// DS_MultiHeadLatentAttention, round 13.
// attn10: attn8's verified math + pipeline, restructured for stall coverage.
// Diagnosis r2/r4: MFMA work ~7us, VALU ~22us, yet attn ~50us -- 47% of
// cycles NO pipe issues. Cause: paired blocks are identical-length and
// phase-locked (launch together, uniform 33-chunk sweeps, same barrier
// cadence) so co-resident blocks stall simultaneously. Fix:
//  - 4-wave blocks (256 thr), one 64-row q-tile each, grid 1024.
//  - LDS 33KB (K dbuf 16K + V 8K + Ps 9K) -> 4 blocks/CU; co-resident
//    blocks have DIFFERENT lengths -> phases drift -> stalls covered.
//  - balance: tile = (slot&1) ? cu : 31-cu pairs long+short per CU slot
//    (66 chunks/CU) under round-robin dispatch, without phase-locking.
//  - no cross-group combine: each wave owns its 16 q-rows end-to-end.
// Pipeline per chunk (counted vmcnt, K dbuf, V early): issue V(c),K(c+1) ->
// vmcnt(4) [K(c)] -> B1 -> QK+sm (covers V) -> vmcnt(2) [V(c)] -> B2 -> PV
// -> B3. Final K-issue clamped (uniform counts). prep/gemms unchanged.
// Dispatches: prep, gemmQLat(640), gemmKV(1024), attn(1024), gemmO(512).
// Workspace (34 MB, time-phased):
//   [0,8M)   Qp      [8,16M)  Kb -> Kp      [16,24M) Qb -> VpT
//   [24,32M) WqT(2M)|Lat(2M)|WdT(.5M)|WkvT(1M) -> Attn
//   [32,34M) WoT
// ---------------------------------------------------------------------------

#define DM 1024
#define NH 16
#define DK 64
#define LL 2048

typedef float  f32x4  __attribute__((ext_vector_type(4)));
typedef __bf16 bf16x8 __attribute__((ext_vector_type(8)));
typedef short  s16x8  __attribute__((ext_vector_type(8)));

__device__ __forceinline__ unsigned short f2bf(float f) {
    union { float f; unsigned int u; } v; v.f = f;
    return (unsigned short)((v.u + 0x7fffu + ((v.u >> 16) & 1u)) >> 16);
}
__device__ __forceinline__ unsigned int pack2(float a, float b) {
    return (unsigned int)f2bf(a) | ((unsigned int)f2bf(b) << 16);
}
// truncating pack (exp values only)
__device__ __forceinline__ unsigned int packt(float a, float b) {
    union { float f; unsigned int u; } x, y; x.f = a; y.f = b;
    return (x.u >> 16) | (y.u & 0xffff0000u);
}
__device__ __forceinline__ bf16x8 ld8(const unsigned short* p) {
    s16x8 s = *(const s16x8*)p;
    return __builtin_bit_cast(bf16x8, s);
}
__device__ __forceinline__ void gl16(const void* g, void* l) {
    __builtin_amdgcn_global_load_lds((__attribute__((address_space(1))) void*)(g),
                                     (__attribute__((address_space(3))) void*)(l),
                                     16, 0, 0);
}

// ---------------------------------------------------------------------------
// prep: 5 weight transposes (fp32 [K][N] -> bf16 [N][K]) + queries/keys
// fp32 -> bf16. Grid = 4864.
// ---------------------------------------------------------------------------
__global__ __launch_bounds__(256)
void prep_k(const float* __restrict__ Wq, const float* __restrict__ Wd,
            const float* __restrict__ Wk, const float* __restrict__ Wv,
            const float* __restrict__ Wo, const float* __restrict__ queries,
            const float* __restrict__ keys,
            unsigned short* __restrict__ WqT, unsigned short* __restrict__ WdT,
            unsigned short* __restrict__ WkvT, unsigned short* __restrict__ WoT,
            unsigned short* __restrict__ Qb, unsigned short* __restrict__ Kb) {
    int bid = blockIdx.x;
    const int t = threadIdx.x;

    const float* W; unsigned short* WT; int TK, TN;
    if (bid < 1024)      { W = Wq; WT = WqT;  TK = 1024; TN = 1024; }
    else if (bid < 1280) { bid -= 1024; W = Wd; WT = WdT; TK = 1024; TN = 256; }
    else if (bid < 1536) { bid -= 1280; W = Wk; WT = WkvT; TK = 256; TN = 1024; }
    else if (bid < 1792) { bid -= 1536; W = Wv; WT = WkvT + (size_t)1024 * 256; TK = 256; TN = 1024; }
    else if (bid < 2816) { bid -= 1792; W = Wo; WT = WoT;  TK = 1024; TN = 1024; }
    else {
        bid -= 2816;
        const float* src; unsigned short* dst;
        if (bid < 1024) { src = queries; dst = Qb; }
        else            { bid -= 1024; src = keys; dst = Kb; }
        const size_t base = (size_t)bid * 4096;
#pragma unroll
        for (int i = 0; i < 4; ++i) {
            float4 f = *(const float4*)(src + base + (size_t)(i * 256 + t) * 4);
            uint2 u = { pack2(f.x, f.y), pack2(f.z, f.w) };
            *(uint2*)(dst + base + (size_t)(i * 256 + t) * 4) = u;
        }
        return;
    }
    __shared__ float tile[32][33];
    const int tx = t & 31, ty = t >> 5;
    const int bx = bid % (TK / 32), by = bid / (TK / 32);
    const int k0 = bx * 32, n0 = by * 32;
#pragma unroll
    for (int i = 0; i < 4; ++i)
        tile[ty + 8 * i][tx] = W[(size_t)(k0 + ty + 8 * i) * TN + n0 + tx];
    __syncthreads();
#pragma unroll
    for (int i = 0; i < 4; ++i)
        WT[(size_t)(n0 + ty + 8 * i) * TK + k0 + tx] = f2bf(tile[tx][ty + 8 * i]);
}

// ---------------------------------------------------------------------------
// GEMM staging + compute helpers (128x64 tile, BK=64).
// ---------------------------------------------------------------------------
__device__ __forceinline__ void stage6(const unsigned short* gA, const unsigned short* gB,
                                       int kk, int K,
                                       unsigned short* lA, unsigned short* lB) {
#pragma unroll
    for (int s = 0; s < 4; ++s) gl16(gA + kk + (size_t)s * 8 * K, lA + s * 512);
#pragma unroll
    for (int s = 0; s < 2; ++s) gl16(gB + kk + (size_t)s * 8 * K, lB + s * 512);
}

__device__ __forceinline__ void mfma16(const unsigned short* As, const unsigned short* Bs,
                                       const int aoff[4][2], const int boff[2][2],
                                       f32x4 acc[4][2]) {
#pragma unroll
    for (int ks = 0; ks < 2; ++ks) {
        bf16x8 a[4], b[2];
#pragma unroll
        for (int i = 0; i < 4; ++i) a[i] = ld8(As + aoff[i][ks]);
#pragma unroll
        for (int j = 0; j < 2; ++j) b[j] = ld8(Bs + boff[j][ks]);
#pragma unroll
        for (int i = 0; i < 4; ++i)
#pragma unroll
            for (int j = 0; j < 2; ++j)
                acc[i][j] = __builtin_amdgcn_mfma_f32_16x16x32_bf16(a[i], b[j], acc[i][j], 0, 0, 0);
    }
}

// ---------------------------------------------------------------------------
// GEMM 128(M) x 64(N) tile, BK=64, 4 waves 2x2 (wave = 64m x 32n, 4x2 accs).
// LDS double-buffer (Sh0/Sh1, compile-time selection), one barrier per iter.
// XCD-clustered: xcd = bid&7 sweeps all n over a small m-window.
// MODE 0: fused Q+Lat (K=1024). bid<512: Qb@WqT+bq -> Qp bf16 [row*1024].
//         bid>=512 (128 blocks): Kb@WdT+bd -> Lat bf16 [row*256].
// MODE 1: Attn@WoT+bo -> f32 [row*1024]. grid 512, K=1024.
// MODE 2: fused K|V (K=256, N=2048): col<1024 -> Kp bf16 [row*1024];
//         col>=1024 -> VpT [b][col-1024][l] via LDS-transposed epilogue.
// ---------------------------------------------------------------------------
template<int MODE>
__global__ __launch_bounds__(256)
void gemm_k(const unsigned short* __restrict__ Ap, const unsigned short* __restrict__ Bt,
            const float* __restrict__ bias, void* __restrict__ Cp,
            const unsigned short* __restrict__ Ap2, const unsigned short* __restrict__ Bt2,
            const float* __restrict__ bias2, void* __restrict__ Cp2,
            int K) {
    __shared__ unsigned short Sh0[12288];     // As0 8192 + Bs0 4096 shorts (24 KB)
    __shared__ unsigned short Sh1[12288];     // As1 + Bs1 (24 KB)

    int bid = blockIdx.x;
    const unsigned short* A;
    const unsigned short* B;
    const float* bs;
    bool second = false;
    int m0, n0;
    if (MODE == 0 && bid >= 512) {            // Lat part: 128 blocks, N=256
        bid -= 512; A = Ap2; B = Bt2; bs = bias2; second = true;
        const int xcd = bid & 7, s = bid >> 3;            // s in [0,16)
        n0 = (s & 3) * 64; m0 = (xcd * 4 + (s >> 2)) * 128;
    } else {
        A = Ap; B = Bt; bs = bias;
        const int xcd = bid & 7, s = bid >> 3;
        if (MODE == 2) { n0 = (s & 31) * 64; m0 = (xcd * 4 + (s >> 5)) * 128; }
        else           { n0 = (s & 15) * 64; m0 = (xcd * 4 + (s >> 4)) * 128; }
    }

    const int t = threadIdx.x, lane = t & 63, wv = t >> 6;
    const int quad = lane >> 4, l15 = lane & 15;

    const int lr8 = lane >> 3;                 // 0..7
    const int g8 = (lane & 7) ^ (lr8 & 7);     // swizzled k-chunk
    const unsigned short* gA = A + (size_t)(m0 + wv * 32 + lr8) * K + g8 * 8;
    const unsigned short* gB = B + (size_t)(n0 + wv * 16 + lr8) * K + g8 * 8;
    unsigned short* lA0 = Sh0 + wv * 2048;
    unsigned short* lB0 = Sh0 + 8192 + wv * 1024;
    unsigned short* lA1 = Sh1 + wv * 2048;
    unsigned short* lB1 = Sh1 + 8192 + wv * 1024;

    int aoff[4][2], boff[2][2];
#pragma unroll
    for (int i = 0; i < 4; ++i) {
        const int ra = (wv >> 1) * 64 + i * 16 + l15;
#pragma unroll
        for (int ks = 0; ks < 2; ++ks)
            aoff[i][ks] = ra * 64 + (((ks * 4 + quad) ^ (ra & 7)) << 3);
    }
#pragma unroll
    for (int j = 0; j < 2; ++j) {
        const int rb = (wv & 1) * 32 + j * 16 + l15;
#pragma unroll
        for (int ks = 0; ks < 2; ++ks)
            boff[j][ks] = rb * 64 + (((ks * 4 + quad) ^ (rb & 7)) << 3);
    }

    f32x4 acc[4][2] = {};
    const int niter = K >> 6;                  // 16 or 4 (always even)

    stage6(gA, gB, 0, K, lA0, lB0);
    __syncthreads();                           // tile 0 resident in Sh0
    for (int it = 0; it < niter; it += 2) {
        const int kk = it << 6;
        // even iter: prefetch -> Sh1, compute Sh0
        if (it + 1 < niter) stage6(gA, gB, kk + 64, K, lA1, lB1);
        mfma16(Sh0, Sh0 + 8192, aoff, boff, acc);
        __syncthreads();                       // drains Sh1 gl16s (overlapped)
        if (it + 1 < niter) {
            // odd iter: prefetch -> Sh0, compute Sh1
            if (it + 2 < niter) stage6(gA, gB, kk + 128, K, lA0, lB0);
            mfma16(Sh1, Sh1 + 8192, aoff, boff, acc);
            __syncthreads();
        }
    }

    const bool isV = (MODE == 2) && (n0 >= 1024);
    if (!isV) {
#pragma unroll
        for (int j = 0; j < 2; ++j) {
            const int col = n0 + (wv & 1) * 32 + j * 16 + l15;
            const float bvv = bs[col];
#pragma unroll
            for (int i = 0; i < 4; ++i) {
                const int rowb = m0 + (wv >> 1) * 64 + i * 16 + quad * 4;
#pragma unroll
                for (int r = 0; r < 4; ++r) {
                    const float v = acc[i][j][r] + bvv;
                    const int row = rowb + r;
                    if (MODE == 1)
                        ((float*)Cp)[(size_t)row * 1024 + col] = v;
                    else if (second)
                        ((unsigned short*)Cp2)[(size_t)row * 256 + col] = f2bf(v);
                    else
                        ((unsigned short*)Cp)[(size_t)row * 1024 + col] = f2bf(v);
                }
            }
        }
    } else {
        // V part: transpose 128tok x 64d tile through LDS, store coalesced
        // to VpT[(b*1024 + d)*2048 + l].  Ld layout: [d][tok], stride 136.
        unsigned short* Ld = Sh0;               // 64*136 shorts = 17408 B
#pragma unroll
        for (int j = 0; j < 2; ++j) {
            const int dloc = (wv & 1) * 32 + j * 16 + l15;
            const float bvv = bias2[(n0 - 1024) + dloc];
#pragma unroll
            for (int i = 0; i < 4; ++i) {
                const int tokb = (wv >> 1) * 64 + i * 16 + quad * 4;
#pragma unroll
                for (int r = 0; r < 4; ++r)
                    Ld[dloc * 136 + tokb + r] = f2bf(acc[i][j][r] + bvv);
            }
        }
        __syncthreads();
        const int dloc = t >> 2;                // 0..63
        const int tk0 = (t & 3) * 32;           // 0,32,64,96
        const int bb = m0 >> 11;
        unsigned short* dst = (unsigned short*)Cp2 +
            ((size_t)bb * 1024 + (n0 - 1024) + dloc) * LL + (m0 & (LL - 1)) + tk0;
        const unsigned short* srcp = Ld + dloc * 136 + tk0;
#pragma unroll
        for (int c = 0; c < 4; ++c)
            *(uint4*)(dst + c * 8) = *(const uint4*)(srcp + c * 8);
    }
}

// ---------------------------------------------------------------------------
// attn helpers: swapped QK^T + fixed-shift softmax -> Ps; PV accumulate.
// ---------------------------------------------------------------------------
__device__ __forceinline__ void qk_sm(const unsigned short* Kc,
        const bf16x8 aq0, const bf16x8 aq1, int rowq, int kt, bool diag,
        int l15, int quad, int sw, unsigned short* PsW, float& lsum) {
#pragma unroll
    for (int sub = 0; sub < 4; ++sub) {
        const int base2 = (sub * 16 + l15) * 64;
        const bf16x8 k0 = ld8(Kc + base2 + ((quad ^ sw) << 3));
        const bf16x8 k1 = ld8(Kc + base2 + (((4 + quad) ^ sw) << 3));
        f32x4 ss = {};
        __builtin_amdgcn_s_setprio(1);
        ss = __builtin_amdgcn_mfma_f32_16x16x32_bf16(k0, aq0, ss, 0, 0, 0);
        ss = __builtin_amdgcn_mfma_f32_16x16x32_bf16(k1, aq1, ss, 0, 0, 0);
        __builtin_amdgcn_s_setprio(0);
        float e[4];
        if (diag) {                            // diagonal chunk: causal mask
            const int kb4 = kt + sub * 16 + quad * 4;
#pragma unroll
            for (int r = 0; r < 4; ++r) {
                const float x = exp2f(fmaf(ss[r], 0.18033688011112042f, -16.0f));
                e[r] = (kb4 + r > rowq) ? 0.f : x;
            }
        } else {                               // interior: no mask
#pragma unroll
            for (int r = 0; r < 4; ++r)
                e[r] = exp2f(fmaf(ss[r], 0.18033688011112042f, -16.0f));
        }
        lsum += (e[0] + e[1]) + (e[2] + e[3]);
        uint2 w2;
        w2.x = packt(e[0], e[1]);
        w2.y = packt(e[2], e[3]);
        *(uint2*)(PsW + l15 * 72 + sub * 16 + quad * 4) = w2;
    }
}

__device__ __forceinline__ void pv_acc(const unsigned short* PsW, const unsigned short* Vg,
        int l15, int quad, int sw, f32x4 acc[4]) {
#pragma unroll
    for (int ks = 0; ks < 2; ++ks) {
        const bf16x8 ap = ld8(PsW + l15 * 72 + ks * 32 + quad * 8);
        __builtin_amdgcn_s_setprio(1);
#pragma unroll
        for (int sub = 0; sub < 4; ++sub) {
            const bf16x8 bv = ld8(Vg + (sub * 16 + l15) * 64 + (((ks * 4 + quad) ^ sw) << 3));
            acc[sub] = __builtin_amdgcn_mfma_f32_16x16x32_bf16(ap, bv, acc[sub], 0, 0, 0);
        }
        __builtin_amdgcn_s_setprio(0);
    }
}

// ---------------------------------------------------------------------------
// attn10: 4-wave blocks (256 thr), one 64-row q-tile per block, grid 1024 =
// 32 combos x 32 tiles. LDS 33KB -> 4 blocks/CU; co-resident blocks have
// different sweep lengths -> phase drift covers barrier/vmcnt stalls.
// Balance: cu = s&31, slot = s>>5; tile = (slot&1) ? cu : 31-cu pairs
// long+short tiles per CU under round-robin dispatch. combo = xcd*4+slot
// keeps each combo's K/V on one XCD's L2.
// Per chunk c=0..tile: issue V(c)+K(c+1 clamped) -> vmcnt(4) [K(c)] -> B1 ->
// QK+sm -> vmcnt(2) [V(c)] -> B2 -> PV -> B3. Wave-local epilogue (no CB).
// ---------------------------------------------------------------------------
__global__ __launch_bounds__(256, 4)
void attn10_k(const unsigned short* __restrict__ Qp,
              const unsigned short* __restrict__ Kp,
              const unsigned short* __restrict__ VpT,
              unsigned short* __restrict__ Op) {
    __shared__ unsigned short Ks[2][4096];     // dbuf [64k x 64d] (16 KB)
    __shared__ unsigned short Vs[4096];        // [64d x 64k]      (8 KB)
    __shared__ unsigned short Ps[4][1152];     // per-wave [16q][72k] (9 KB)

    const int t = threadIdx.x, lane = t & 63, wv = t >> 6;
    const int quad = lane >> 4, l15 = lane & 15;

    const int bid = blockIdx.x;
    const int xcd = bid & 7, s = bid >> 3;     // s in [0,128)
    const int cu = s & 31, slot = s >> 5;      // round-robin CU / resident slot
    const int combo = xcd * 4 + slot;          // 4 combos per XCD (L2 locality)
    const int tile = (slot & 1) ? cu : (31 - cu);   // long+short per CU
    const int h = combo & 15, b = combo >> 4;
    const int q0 = tile * 64;

    const int srow = wv * 16 + (lane >> 3);
    const int g8 = (lane & 7) ^ ((lane >> 3) & 7);
    const int sw = l15 & 7;
    unsigned short* PsW = Ps[wv];

    const unsigned short* Kbase = Kp + (size_t)(b * LL + srow) * DM + h * DK + g8 * 8;
    const unsigned short* Vbase = VpT + ((size_t)(b * NH + h) * DK + srow) * LL + g8 * 8;
    unsigned short* lV = Vs + wv * 1024;

    const int rowq = q0 + wv * 16 + l15;       // this lane's q-row
    const unsigned short* qp = Qp + (size_t)(b * LL + rowq) * DM + h * DK;
    const bf16x8 aq0 = ld8(qp + quad * 8);
    const bf16x8 aq1 = ld8(qp + 32 + quad * 8);

    f32x4 acc[4] = {};
    float lsum = 0.f;

    // prologue: stage K(0) -> Ks[0]
    gl16(Kbase, Ks[0] + wv * 1024);
    gl16(Kbase + (size_t)8 * DM, Ks[0] + wv * 1024 + 512);

    for (int c = 0; c <= tile; ++c) {
        const int cur = c & 1;
        const int kt = c * 64;

        // issue V(c) -> Vs (consumed after B2); K(c+1) -> Ks[cur^1] (clamped)
        const unsigned short* vg = Vbase + kt;
        gl16(vg, lV); gl16(vg + (size_t)8 * LL, lV + 512);
        const int c2 = (c + 1 <= tile) ? (c + 1) : tile;
        const unsigned short* kg = Kbase + (size_t)(c2 * 64) * DM;
        unsigned short* lK = Ks[cur ^ 1] + wv * 1024;
        gl16(kg, lK); gl16(kg + (size_t)8 * DM, lK + 512);

        asm volatile("s_waitcnt vmcnt(4)" ::: "memory");  // K(c) landed
        __builtin_amdgcn_s_barrier();                     // B1
        __builtin_amdgcn_sched_barrier(0);

        qk_sm(Ks[cur], aq0, aq1, rowq, kt, c == tile, l15, quad, sw, PsW, lsum);

        asm volatile("s_waitcnt vmcnt(2)" ::: "memory");  // V(c) landed
        __builtin_amdgcn_s_barrier();                     // B2
        __builtin_amdgcn_sched_barrier(0);

        pv_acc(PsW, Vs, l15, quad, sw, acc);

        __builtin_amdgcn_s_barrier();                     // B3: Vs/Ks free
        __builtin_amdgcn_sched_barrier(0);
    }
    asm volatile("s_waitcnt vmcnt(0)" ::: "memory");      // drain tail K issue

    // wave-local epilogue: reduce lsum across quads, normalize, write out
    lsum += __shfl_xor(lsum, 16, 64);
    lsum += __shfl_xor(lsum, 32, 64);
    const float inv = __builtin_amdgcn_rcpf(lsum);
    float invr[4];
#pragma unroll
    for (int r = 0; r < 4; ++r) invr[r] = __shfl(inv, quad * 4 + r, 64);
#pragma unroll
    for (int sub = 0; sub < 4; ++sub)
#pragma unroll
        for (int r = 0; r < 4; ++r)
            Op[(size_t)(b * LL + q0 + wv * 16 + quad * 4 + r) * DM + h * DK + sub * 16 + l15] =
                f2bf(acc[sub][r] * invr[r]);
}

// ---------------------------------------------------------------------------
extern "C" void kernel_launch(void* const* d_in, const int* in_sizes, int n_in,
                              void* d_out, int out_size, void* d_ws, size_t ws_size,
                              hipStream_t stream) {
    const float* queries = (const float*)d_in[0];
    const float* keys    = (const float*)d_in[1];
    const float* Wq = (const float*)d_in[3];  const float* bq = (const float*)d_in[4];
    const float* Wd = (const float*)d_in[5];  const float* bd = (const float*)d_in[6];
    const float* Wk = (const float*)d_in[7];  const float* bk = (const float*)d_in[8];
    const float* Wv = (const float*)d_in[9];  const float* bv = (const float*)d_in[10];
    const float* Wo = (const float*)d_in[11]; const float* bo = (const float*)d_in[12];

    char* ws = (char*)d_ws;
    const size_t MB = 1048576;
    unsigned short* Qp   = (unsigned short*)(ws);
    unsigned short* Kb   = (unsigned short*)(ws + 8 * MB);
    unsigned short* Kp   = (unsigned short*)(ws + 8 * MB);
    unsigned short* Qb   = (unsigned short*)(ws + 16 * MB);
    unsigned short* VpT  = (unsigned short*)(ws + 16 * MB);
    unsigned short* WqT  = (unsigned short*)(ws + 24 * MB);
    unsigned short* Lat  = (unsigned short*)(ws + 26 * MB);
    unsigned short* WdT  = (unsigned short*)(ws + 28 * MB);
    unsigned short* WkvT = (unsigned short*)(ws + 28 * MB + 524288);
    unsigned short* Attn = (unsigned short*)(ws + 24 * MB);
    unsigned short* WoT  = (unsigned short*)(ws + 32 * MB);

    prep_k<<<4864, 256, 0, stream>>>(Wq, Wd, Wk, Wv, Wo, queries, keys,
                                     WqT, WdT, WkvT, WoT, Qb, Kb);
    gemm_k<0><<<640, 256, 0, stream>>>(Qb, WqT, bq, Qp, Kb, WdT, bd, Lat, 1024);
    gemm_k<2><<<1024, 256, 0, stream>>>(Lat, WkvT, bk, Kp, nullptr, nullptr, bv, VpT, 256);
    attn10_k<<<1024, 256, 0, stream>>>(Qp, Kp, VpT, Attn);
    gemm_k<1><<<512, 256, 0, stream>>>(Attn, WoT, bo, d_out, nullptr, nullptr, nullptr, nullptr, 1024);
}